// Round 7
// baseline (61232.593 us; speedup 1.0000x reference)
//
#include <hip/hip_runtime.h>
#include <hip/hip_bf16.h>

#define TT 512
#define NB 1024

typedef float f32x4 __attribute__((ext_vector_type(4)));
typedef __bf16 bf16x8 __attribute__((ext_vector_type(8)));
typedef __bf16 bf16x4 __attribute__((ext_vector_type(4)));

// ---- packed weight layout in d_ws (bf16 elems), π-fragment form (verified R3-R6):
//   frag(mt, kt, lane, j) at OFF + ((mt*KT + kt)*512 + lane*8 + j)
//   value = W[kappa][16*mt + (lane&15)]
//   perm matrices (consume exchanged activations): kappa = 32*kt + 16*(j>>2) + 4*lq + (j&3)
//   Wcp (consumes x): kappa = 32*kt + 8*lq + j
#define OFF_HP 0
#define OFF_CP 65536
#define OFF_M  81920
#define OFF_PO 212992
#define OFF_R1 278528
#define TOT    344064

// exchange regions (bf16 elem offsets within d_ws)
#define EX_CAT 524288    // byte 1 MB: 32 groups x 16 kt x 2 rt x 1KB = 1 MB
#define EX_U   1048576   // byte 2 MB: 512 KB
#define EX_H   1310720   // byte 2.5 MB: 512 KB
#define FLAGS_BYTE (3*1024*1024)
#define WS_NEED (3*1024*1024 + 8192)

__global__ __launch_bounds__(256) void pack_weights(
    const float* __restrict__ Whp, const float* __restrict__ Wm,
    const float* __restrict__ Wcp, const float* __restrict__ Whpost,
    const float* __restrict__ Wr1, __bf16* __restrict__ wsp) {
  int id = blockIdx.x * 256 + threadIdx.x;
  if (id >= TOT) return;
  int j = id & 7, lane = (id >> 3) & 63;
  int lq = lane >> 4, l15 = lane & 15;
  int rel, KT; const float* W; bool perm = true;
  if (id < OFF_CP)      { rel = id;          KT = 8;  W = Whp; }
  else if (id < OFF_M)  { rel = id - OFF_CP; KT = 2;  W = Wcp; perm = false; }
  else if (id < OFF_PO) { rel = id - OFF_M;  KT = 16; W = Wm; }
  else if (id < OFF_R1) { rel = id - OFF_PO; KT = 8;  W = Whpost; }
  else                  { rel = id - OFF_R1; KT = 8;  W = Wr1; }
  int ktm = rel >> 9;
  int kt = ktm % KT, mt = ktm / KT;
  int phi = 16 * mt + l15;
  int kk;
  if (perm) {
    int kb = (kt >= 8) ? kt - 8 : kt;          // only mesh has kt>=8
    kk = 32 * kb + 16 * (j >> 2) + 4 * lq + (j & 3);
    if (kt >= 8) kk += 256;                    // cp half of the concat
  } else {
    kk = 32 * kt + 8 * lq + j;
  }
  wsp[id] = (__bf16)W[kk * 256 + phi];
}

__device__ __forceinline__ float tanh_fast(float x) {
  float t = __expf(2.0f * x);
  return 1.0f - __fdividef(2.0f, t + 1.0f);
}

__device__ __forceinline__ bf16x4 tanh4(const f32x4& a) {
  bf16x4 f;
  #pragma unroll
  for (int r = 0; r < 4; ++r) f[r] = (__bf16)tanh_fast(a[r]);
  return f;
}

#define MFMA(a, b, c) __builtin_amdgcn_mfma_f32_16x16x32_bf16((a), (b), (c), 0, 0, 0)

__device__ __forceinline__ void lds_copy(__bf16* dst, const __bf16* src, int nvec,
                                         int tid) {
  for (int i = tid; i < nvec; i += 256)
    ((bf16x8*)dst)[i] = ((const bf16x8*)src)[i];
}

// all threads spin (uniform), then acquire so subsequent plain loads see fresh data
__device__ __forceinline__ void wait_flag(int* fl, int target) {
  while (__hip_atomic_load(fl, __ATOMIC_RELAXED, __HIP_MEMORY_SCOPE_AGENT) < target)
    __builtin_amdgcn_s_sleep(1);
  __threadfence();   // acquire (agent): invalidate stale caches
}

// publish this WG's stores, then one increment
__device__ __forceinline__ void signal_flag(int* fl, int tid) {
  __threadfence();   // release (agent): drain + write back
  __syncthreads();   // all waves' fences complete
  if (tid == 0) atomicAdd(fl, 1);
}

__global__ __launch_bounds__(256) void rnn_seq(
    const float* __restrict__ x, __bf16* __restrict__ wsb,
    int* __restrict__ flags,
    const float* __restrict__ bhp, const float* __restrict__ bcp,
    const float* __restrict__ bm, const float* __restrict__ bhpost,
    const float* __restrict__ br1, const float* __restrict__ Wr2,
    const float* __restrict__ br2, float* __restrict__ out) {
  // per-WG weight slice, LDS-resident for the whole sequence (86 KB -> 1 WG/CU)
  __shared__ __align__(16) __bf16 ldsw[43008];
  // region offsets (elems): hp 0, cp 8192, m 10240, po 26624, r1 34816

  const int tid  = threadIdx.x;
  const int wv   = tid >> 6;
  const int lane = tid & 63;
  const int lq   = lane >> 4, l15 = lane & 15;
  const int m    = wv & 1;      // m-tile within WG (16 feats)
  const int r    = wv >> 1;     // row-tile (16 rows)

  // swizzle: 8 feature-WGs of a group share presumed XCD = blockIdx%8 (perf only)
  const int c = blockIdx.x & 7, s = blockIdx.x >> 3;
  const int g = c * 4 + (s >> 3);   // batch group 0..31 (32 rows)
  const int f = s & 7;              // feature slice 0..7 (32 feats)

  // ---- one-time: weights global -> LDS ----
  lds_copy(ldsw + 0,     wsb + OFF_HP + (size_t)16 * f * 512, 1024, tid);
  lds_copy(ldsw + 8192,  wsb + OFF_CP + (size_t)4  * f * 512, 256,  tid);
  lds_copy(ldsw + 10240, wsb + OFF_M  + (size_t)32 * f * 512, 2048, tid);
  lds_copy(ldsw + 26624, wsb + OFF_PO + (size_t)16 * f * 512, 1024, tid);
  lds_copy(ldsw + 34816, wsb + OFF_R1 + (size_t)16 * f * 512, 1024, tid);

  // per-wave LDS A-frag bases (elems): region + m*KT*512 + lane*8
  const __bf16* A_hp = ldsw + 0     + m * 8  * 512 + lane * 8;
  const __bf16* A_cp = ldsw + 8192  + m * 2  * 512 + lane * 8;
  const __bf16* A_m  = ldsw + 10240 + m * 16 * 512 + lane * 8;
  const __bf16* A_po = ldsw + 26624 + m * 8  * 512 + lane * 8;
  const __bf16* A_r1 = ldsw + 34816 + m * 8  * 512 + lane * 8;

  // biases for this wave's 4 features: 32f + 16m + 4lq + rr
  const int bo = 32 * f + 16 * m + 4 * lq;
  const f32x4 b_hp = *(const f32x4*)(bhp + bo);
  const f32x4 b_cp = *(const f32x4*)(bcp + bo);
  const f32x4 b_m  = *(const f32x4*)(bm + bo);
  const f32x4 b_po = *(const f32x4*)(bhpost + bo);
  const f32x4 b_r1 = *(const f32x4*)(br1 + bo);
  const f32x4 w2v  = *(const f32x4*)(Wr2 + bo);
  const float br2v = (f == 0 && m == 0) ? br2[0] : 0.0f;

  // exchange pointers (kt stride = 1024 elems; rt = r fixed)
  __bf16* cat_rd = wsb + EX_CAT + (size_t)(g * 32 + r) * 512 + lane * 8;
  __bf16* u_rd   = wsb + EX_U   + (size_t)(g * 16 + r) * 512 + lane * 8;
  __bf16* h_rd   = wsb + EX_H   + (size_t)(g * 16 + r) * 512 + lane * 8;
  __bf16* cat_wr_hp = cat_rd + (size_t)f * 1024 + 4 * m;
  __bf16* cat_wr_cp = cat_rd + (size_t)(8 + f) * 1024 + 4 * m;
  __bf16* u_wr   = u_rd + (size_t)f * 1024 + 4 * m;
  __bf16* h_wr   = h_rd + (size_t)f * 1024 + 4 * m;

  int* fc = flags + g * 48;
  int* fu = fc + 16;
  int* fh = fc + 32;

  const int orow = 32 * g + 16 * r;
  const float* xbase = x + (size_t)(orow + l15) * 64 + 8 * lq;
  f32x4 xr0 = *(const f32x4*)(xbase);
  f32x4 xr1 = *(const f32x4*)(xbase + 4);
  f32x4 xr2 = *(const f32x4*)(xbase + 32);
  f32x4 xr3 = *(const f32x4*)(xbase + 36);

  __syncthreads();  // LDS weights ready

  for (int t = 0; t < TT; ++t) {
    // ---- stage 1: hp = h@Whp+bhp ; cp = x@Wcp+bcp ; r1 partial for out[t-1] ----
    wait_flag(fh, 8 * t);
    bf16x8 Bh[8];
    #pragma unroll
    for (int kt = 0; kt < 8; ++kt) Bh[kt] = *(const bf16x8*)(h_rd + kt * 1024);
    bf16x8 Bx0, Bx1;
    #pragma unroll
    for (int j = 0; j < 4; ++j) {
      Bx0[j] = (__bf16)xr0[j]; Bx0[4 + j] = (__bf16)xr1[j];
      Bx1[j] = (__bf16)xr2[j]; Bx1[4 + j] = (__bf16)xr3[j];
    }
    f32x4 ah = b_hp, ar = b_r1, ac = b_cp;
    #pragma unroll
    for (int kt = 0; kt < 8; ++kt) {
      bf16x8 a = *(const bf16x8*)(A_hp + kt * 512);
      ah = MFMA(a, Bh[kt], ah);
      bf16x8 a2 = *(const bf16x8*)(A_r1 + kt * 512);
      ar = MFMA(a2, Bh[kt], ar);
    }
    ac = MFMA(*(const bf16x8*)(A_cp), Bx0, ac);
    ac = MFMA(*(const bf16x8*)(A_cp + 512), Bx1, ac);
    *(bf16x4*)cat_wr_hp = tanh4(ah);
    *(bf16x4*)cat_wr_cp = tanh4(ac);
    if (t > 0) {
      float p = 0.f;
      #pragma unroll
      for (int rr = 0; rr < 4; ++rr) p += fmaxf(ar[rr], 0.f) * w2v[rr];
      p += __shfl_xor(p, 16, 64);
      p += __shfl_xor(p, 32, 64);
      if (lane < 16)
        atomicAdd(out + (size_t)(t - 1) * NB + orow + lane, p + br2v);
    }
    signal_flag(fc, tid);

    // ---- stage 2: u = cat @ Wm + bm (Wm in LDS) ----
    wait_flag(fc, 8 * (t + 1));
    {  // prefetch next x early so the release fence doesn't stall on it
      int tn = (t + 1 < TT) ? t + 1 : TT - 1;
      const float* xp = xbase + (size_t)tn * NB * 64;
      xr0 = *(const f32x4*)(xp);      xr1 = *(const f32x4*)(xp + 4);
      xr2 = *(const f32x4*)(xp + 32); xr3 = *(const f32x4*)(xp + 36);
    }
    bf16x8 Bc[16];
    #pragma unroll
    for (int kt = 0; kt < 16; ++kt) Bc[kt] = *(const bf16x8*)(cat_rd + kt * 1024);
    f32x4 am = b_m;
    #pragma unroll
    for (int kt = 0; kt < 16; ++kt) {
      bf16x8 a = *(const bf16x8*)(A_m + kt * 512);
      am = MFMA(a, Bc[kt], am);
    }
    *(bf16x4*)u_wr = tanh4(am);
    signal_flag(fu, tid);

    // ---- stage 3: h = tanh(u @ Whpost + bhpost) ----
    wait_flag(fu, 8 * (t + 1));
    bf16x8 Bu[8];
    #pragma unroll
    for (int kt = 0; kt < 8; ++kt) Bu[kt] = *(const bf16x8*)(u_rd + kt * 1024);
    f32x4 ap = b_po;
    #pragma unroll
    for (int kt = 0; kt < 8; ++kt) {
      bf16x8 a = *(const bf16x8*)(A_po + kt * 512);
      ap = MFMA(a, Bu[kt], ap);
    }
    *(bf16x4*)h_wr = tanh4(ap);
    signal_flag(fh, tid);
  }

  // ---- tail: regressor on final h -> out[TT-1] ----
  wait_flag(fh, 8 * TT);
  {
    bf16x8 Bh[8];
    #pragma unroll
    for (int kt = 0; kt < 8; ++kt) Bh[kt] = *(const bf16x8*)(h_rd + kt * 1024);
    f32x4 ar = b_r1;
    #pragma unroll
    for (int kt = 0; kt < 8; ++kt) {
      bf16x8 a = *(const bf16x8*)(A_r1 + kt * 512);
      ar = MFMA(a, Bh[kt], ar);
    }
    float p = 0.f;
    #pragma unroll
    for (int rr = 0; rr < 4; ++rr) p += fmaxf(ar[rr], 0.f) * w2v[rr];
    p += __shfl_xor(p, 16, 64);
    p += __shfl_xor(p, 32, 64);
    if (lane < 16)
      atomicAdd(out + (size_t)(TT - 1) * NB + orow + lane, p + br2v);
  }
}

extern "C" void kernel_launch(void* const* d_in, const int* in_sizes, int n_in,
                              void* d_out, int out_size, void* d_ws, size_t ws_size,
                              hipStream_t stream) {
  const float* x      = (const float*)d_in[0];
  const float* Whp    = (const float*)d_in[1];
  const float* bhp    = (const float*)d_in[2];
  const float* Wcp    = (const float*)d_in[3];
  const float* bcp    = (const float*)d_in[4];
  const float* Wm     = (const float*)d_in[5];
  const float* bm     = (const float*)d_in[6];
  const float* Whpost = (const float*)d_in[7];
  const float* bhpost = (const float*)d_in[8];
  const float* Wr1    = (const float*)d_in[9];
  const float* br1    = (const float*)d_in[10];
  const float* Wr2    = (const float*)d_in[11];
  const float* br2    = (const float*)d_in[12];
  __bf16* wsb = (__bf16*)d_ws;
  int* flags  = (int*)((char*)d_ws + FLAGS_BYTE);
  float* out  = (float*)d_out;

  if (ws_size < (size_t)WS_NEED) return;

  hipMemsetAsync(out, 0, (size_t)out_size * sizeof(float), stream);
  // zero exchange regions (h(0)=0) + flags
  hipMemsetAsync((char*)d_ws + (1 << 20), 0, (2 << 20) + 8192, stream);
  pack_weights<<<(TOT + 255) / 256, 256, 0, stream>>>(Whp, Wm, Wcp, Whpost, Wr1, wsb);
  rnn_seq<<<256, 256, 0, stream>>>(x, wsb, flags, bhp, bcp, bm, bhpost, br1,
                                   Wr2, br2, out);
}

// Round 8
// 6329.652 us; speedup vs baseline: 9.6739x; 9.6739x over previous
//
#include <hip/hip_runtime.h>
#include <hip/hip_bf16.h>

#define TT 512
#define NB 1024

typedef float f32x4 __attribute__((ext_vector_type(4)));
typedef __bf16 bf16x8 __attribute__((ext_vector_type(8)));

// ---- packed weight layout in d_ws (bf16 elems), π-fragment form (verified R3-R7):
//   frag(mt, kt, lane, j) at OFF + ((mt*KT + kt)*512 + lane*8 + j)
//   value = W[kappa][16*mt + (lane&15)]
//   perm matrices: kappa = 32*kt + 16*(j>>2) + 4*(lane>>4) + (j&3)
//   Wcp (consumes x): kappa = 32*kt + 8*(lane>>4) + j
#define OFF_HP 0
#define OFF_CP 65536
#define OFF_M  81920
#define OFF_PO 212992
#define OFF_R1 278528
#define TOT    344064

__global__ __launch_bounds__(256) void pack_weights(
    const float* __restrict__ Whp, const float* __restrict__ Wm,
    const float* __restrict__ Wcp, const float* __restrict__ Whpost,
    const float* __restrict__ Wr1, __bf16* __restrict__ wsp) {
  int id = blockIdx.x * 256 + threadIdx.x;
  if (id >= TOT) return;
  int j = id & 7, lane = (id >> 3) & 63;
  int lq = lane >> 4, l15 = lane & 15;
  int rel, KT; const float* W; bool perm = true;
  if (id < OFF_CP)      { rel = id;          KT = 8;  W = Whp; }
  else if (id < OFF_M)  { rel = id - OFF_CP; KT = 2;  W = Wcp; perm = false; }
  else if (id < OFF_PO) { rel = id - OFF_M;  KT = 16; W = Wm; }
  else if (id < OFF_R1) { rel = id - OFF_PO; KT = 8;  W = Whpost; }
  else                  { rel = id - OFF_R1; KT = 8;  W = Wr1; }
  int ktm = rel >> 9;
  int kt = ktm % KT, mt = ktm / KT;
  int phi = 16 * mt + l15;
  int kk;
  if (perm) {
    int kb = (kt >= 8) ? kt - 8 : kt;          // only mesh has kt>=8
    kk = 32 * kb + 16 * (j >> 2) + 4 * lq + (j & 3);
    if (kt >= 8) kk += 256;                    // cp half of the concat
  } else {
    kk = 32 * kt + 8 * lq + j;
  }
  wsp[id] = (__bf16)W[kk * 256 + phi];
}

__device__ __forceinline__ float tanh_fast(float x) {
  float t = __expf(2.0f * x);
  return 1.0f - __fdividef(2.0f, t + 1.0f);
}

#define MFMA(a, b, c) __builtin_amdgcn_mfma_f32_16x16x32_bf16((a), (b), (c), 0, 0, 0)

// tanh + pack this wave's two accumulators into ONE full B-fragment (kt = wv):
// B[wv][j] = tanh(acc[j>>2][j&3]); conflict-free ds_write_b128 at lane*16.
__device__ __forceinline__ void pack2(__bf16* region, int wv, int lane,
                                      const f32x4& a0, const f32x4& a1) {
  bf16x8 f;
  #pragma unroll
  for (int r = 0; r < 4; ++r) {
    f[r]     = (__bf16)tanh_fast(a0[r]);
    f[4 + r] = (__bf16)tanh_fast(a1[r]);
  }
  *(bf16x8*)(region + wv * 512 + lane * 8) = f;
}

__global__ __launch_bounds__(512, 2) void rnn_seq(
    const float* __restrict__ x, const __bf16* __restrict__ wsp,
    const float* __restrict__ bhp, const float* __restrict__ bcp,
    const float* __restrict__ bm, const float* __restrict__ bhpost,
    const float* __restrict__ br1, const float* __restrict__ Wr2,
    const float* __restrict__ br2, float* __restrict__ out) {
  __shared__ __align__(16) __bf16 hB[8 * 512];   // h state as B-frags
  __shared__ __align__(16) __bf16 mB[16 * 512];  // [hpB | cpB] for mesh
  __shared__ __align__(16) __bf16 uB[8 * 512];   // mesh output
  __shared__ float lb[6 * 256];                  // bhp,bcp,bm,bhpost,br1,Wr2
  __shared__ float outp[128];

  const int tid  = threadIdx.x;
  const int wv   = tid >> 6;      // 0..7, owns m-tiles 2wv, 2wv+1
  const int lane = tid & 63;
  const int lq   = lane >> 4, l15 = lane & 15;
  const int n0   = blockIdx.x * 16;
  const int mt0  = 2 * wv;

  if (tid < 256) {
    lb[0 * 256 + tid] = bhp[tid];
    lb[1 * 256 + tid] = bcp[tid];
    lb[2 * 256 + tid] = bm[tid];
    lb[3 * 256 + tid] = bhpost[tid];
    lb[4 * 256 + tid] = br1[tid];
    lb[5 * 256 + tid] = Wr2[tid];
  }
  for (int i = tid; i < 8 * 512; i += 512) hB[i] = (__bf16)0.0f;  // h0 = 0
  const float br2v = br2[0];

  // bias accessor: element r of f32x4 <-> feature 16*mt + 4*lq + r
  #define BIAS(a, m) (*(const f32x4*)(lb + (a) * 256 + (m) * 16 + 4 * lq))
  const f32x4 w2a = *(const f32x4*)(Wr2 + mt0 * 16 + 4 * lq);
  const f32x4 w2b = *(const f32x4*)(Wr2 + (mt0 + 1) * 16 + 4 * lq);

  // A-frag bases for this wave's mt pair: frag(mt0,kt) at +kt*512,
  // frag(mt0+1,kt) at +(KT+kt)*512
  const __bf16* hp_p = wsp + OFF_HP + (size_t)(mt0 * 8) * 512 + lane * 8;
  const __bf16* r1_p = wsp + OFF_R1 + (size_t)(mt0 * 8) * 512 + lane * 8;
  const __bf16* cp_p = wsp + OFF_CP + (size_t)(mt0 * 2) * 512 + lane * 8;
  const __bf16* po_p = wsp + OFF_PO + (size_t)(mt0 * 8) * 512 + lane * 8;
  const __bf16* wm_p = wsp + OFF_M  + (size_t)(mt0 * 16) * 512 + lane * 8;

  const float* xbase = x + (size_t)(n0 + l15) * 64 + 8 * lq;
  f32x4 xr0 = *(const f32x4*)(xbase);
  f32x4 xr1 = *(const f32x4*)(xbase + 4);
  f32x4 xr2 = *(const f32x4*)(xbase + 32);
  f32x4 xr3 = *(const f32x4*)(xbase + 36);

  __syncthreads();

  for (int t = 0; t < TT; ++t) {
    // ---- stage 1: hp = h@Whp+bhp (dual with r1 = h@Wr1+br1) ; cp = x@Wcp+bcp ----
    // cp frags issued first: latency hides under the whole kt loop
    bf16x8 cpw[4];
    #pragma unroll
    for (int p = 0; p < 4; ++p) cpw[p] = *(const bf16x8*)(cp_p + p * 512);
    // rolling window: 2-kt lookahead x {hp(mt0), hp(mt1), r1(mt0), r1(mt1)}
    bf16x8 w[8];
    #pragma unroll
    for (int p = 0; p < 2; ++p) {
      w[4 * p + 0] = *(const bf16x8*)(hp_p + p * 512);
      w[4 * p + 1] = *(const bf16x8*)(hp_p + (8 + p) * 512);
      w[4 * p + 2] = *(const bf16x8*)(r1_p + p * 512);
      w[4 * p + 3] = *(const bf16x8*)(r1_p + (8 + p) * 512);
    }
    bf16x8 Bx0, Bx1;
    #pragma unroll
    for (int j = 0; j < 4; ++j) {
      Bx0[j] = (__bf16)xr0[j]; Bx0[4 + j] = (__bf16)xr1[j];
      Bx1[j] = (__bf16)xr2[j]; Bx1[4 + j] = (__bf16)xr3[j];
    }
    f32x4 ah0 = BIAS(0, mt0), ah1 = BIAS(0, mt0 + 1);
    f32x4 ar0 = BIAS(4, mt0), ar1 = BIAS(4, mt0 + 1);
    #pragma unroll
    for (int kt = 0; kt < 8; ++kt) {
      bf16x8 B = *(const bf16x8*)(hB + kt * 512 + lane * 8);
      int s = (kt & 1) * 4;
      ah0 = MFMA(w[s + 0], B, ah0);
      ah1 = MFMA(w[s + 1], B, ah1);
      ar0 = MFMA(w[s + 2], B, ar0);
      ar1 = MFMA(w[s + 3], B, ar1);
      if (kt + 2 < 8) {
        w[s + 0] = *(const bf16x8*)(hp_p + (kt + 2) * 512);
        w[s + 1] = *(const bf16x8*)(hp_p + (8 + kt + 2) * 512);
        w[s + 2] = *(const bf16x8*)(r1_p + (kt + 2) * 512);
        w[s + 3] = *(const bf16x8*)(r1_p + (8 + kt + 2) * 512);
      }
    }
    f32x4 ac0 = BIAS(1, mt0), ac1 = BIAS(1, mt0 + 1);
    ac0 = MFMA(cpw[0], Bx0, ac0); ac0 = MFMA(cpw[1], Bx1, ac0);
    ac1 = MFMA(cpw[2], Bx0, ac1); ac1 = MFMA(cpw[3], Bx1, ac1);

    pack2(mB,           wv, lane, ah0, ah1);
    pack2(mB + 8 * 512, wv, lane, ac0, ac1);
    {
      float p = 0.f;
      #pragma unroll
      for (int r = 0; r < 4; ++r)
        p += fmaxf(ar0[r], 0.f) * w2a[r] + fmaxf(ar1[r], 0.f) * w2b[r];
      p += __shfl_xor(p, 16, 64);
      p += __shfl_xor(p, 32, 64);
      if (lane < 16) outp[wv * 16 + lane] = p;
    }
    __syncthreads();  // B1

    // ---- stage 2: u = cat @ Wm + bm ; store out[t-1] ; prefetch next x ----
    if (t > 0 && tid < 16) {
      float s = br2v;
      #pragma unroll
      for (int w8 = 0; w8 < 8; ++w8) s += outp[w8 * 16 + tid];
      out[(size_t)(t - 1) * NB + n0 + tid] = s;
    }
    {
      int tn = (t + 1 < TT) ? t + 1 : TT - 1;
      const float* xp = xbase + (size_t)tn * NB * 64;
      xr0 = *(const f32x4*)(xp);      xr1 = *(const f32x4*)(xp + 4);
      xr2 = *(const f32x4*)(xp + 32); xr3 = *(const f32x4*)(xp + 36);
    }
    // rolling window: 6-kt lookahead x {wm(mt0), wm(mt1)}
    bf16x8 m[12];
    #pragma unroll
    for (int p = 0; p < 6; ++p) {
      m[2 * p + 0] = *(const bf16x8*)(wm_p + p * 512);
      m[2 * p + 1] = *(const bf16x8*)(wm_p + (16 + p) * 512);
    }
    f32x4 am0 = BIAS(2, mt0), am1 = BIAS(2, mt0 + 1);
    #pragma unroll
    for (int kt = 0; kt < 16; ++kt) {
      bf16x8 B = *(const bf16x8*)(mB + kt * 512 + lane * 8);
      int s = (kt % 6) * 2;
      am0 = MFMA(m[s + 0], B, am0);
      am1 = MFMA(m[s + 1], B, am1);
      if (kt + 6 < 16) {
        m[s + 0] = *(const bf16x8*)(wm_p + (kt + 6) * 512);
        m[s + 1] = *(const bf16x8*)(wm_p + (16 + kt + 6) * 512);
      }
    }
    pack2(uB, wv, lane, am0, am1);
    __syncthreads();  // B2

    // ---- stage 3: h = tanh(u @ Whpost + bhpost) ----
    // rolling window: 4-kt lookahead x {po(mt0), po(mt1)}
    bf16x8 pw[8];
    #pragma unroll
    for (int p = 0; p < 4; ++p) {
      pw[2 * p + 0] = *(const bf16x8*)(po_p + p * 512);
      pw[2 * p + 1] = *(const bf16x8*)(po_p + (8 + p) * 512);
    }
    f32x4 ap0 = BIAS(3, mt0), ap1 = BIAS(3, mt0 + 1);
    #pragma unroll
    for (int kt = 0; kt < 8; ++kt) {
      bf16x8 B = *(const bf16x8*)(uB + kt * 512 + lane * 8);
      int s = (kt & 3) * 2;
      ap0 = MFMA(pw[s + 0], B, ap0);
      ap1 = MFMA(pw[s + 1], B, ap1);
      if (kt + 4 < 8) {
        pw[s + 0] = *(const bf16x8*)(po_p + (kt + 4) * 512);
        pw[s + 1] = *(const bf16x8*)(po_p + (8 + kt + 4) * 512);
      }
    }
    pack2(hB, wv, lane, ap0, ap1);
    __syncthreads();  // B3
  }

  // ---- tail: regressor on final h ----
  {
    bf16x8 w[8];
    #pragma unroll
    for (int p = 0; p < 4; ++p) {
      w[2 * p + 0] = *(const bf16x8*)(r1_p + p * 512);
      w[2 * p + 1] = *(const bf16x8*)(r1_p + (8 + p) * 512);
    }
    f32x4 ar0 = BIAS(4, mt0), ar1 = BIAS(4, mt0 + 1);
    #pragma unroll
    for (int kt = 0; kt < 8; ++kt) {
      bf16x8 B = *(const bf16x8*)(hB + kt * 512 + lane * 8);
      int s = (kt & 3) * 2;
      ar0 = MFMA(w[s + 0], B, ar0);
      ar1 = MFMA(w[s + 1], B, ar1);
      if (kt + 4 < 8) {
        w[s + 0] = *(const bf16x8*)(r1_p + (kt + 4) * 512);
        w[s + 1] = *(const bf16x8*)(r1_p + (8 + kt + 4) * 512);
      }
    }
    float p = 0.f;
    #pragma unroll
    for (int r = 0; r < 4; ++r)
      p += fmaxf(ar0[r], 0.f) * w2a[r] + fmaxf(ar1[r], 0.f) * w2b[r];
    p += __shfl_xor(p, 16, 64);
    p += __shfl_xor(p, 32, 64);
    if (lane < 16) outp[wv * 16 + lane] = p;
    __syncthreads();
    if (tid < 16) {
      float s = br2v;
      #pragma unroll
      for (int w8 = 0; w8 < 8; ++w8) s += outp[w8 * 16 + tid];
      out[(size_t)(TT - 1) * NB + n0 + tid] = s;
    }
  }
}

extern "C" void kernel_launch(void* const* d_in, const int* in_sizes, int n_in,
                              void* d_out, int out_size, void* d_ws, size_t ws_size,
                              hipStream_t stream) {
  const float* x      = (const float*)d_in[0];
  const float* Whp    = (const float*)d_in[1];
  const float* bhp    = (const float*)d_in[2];
  const float* Wcp    = (const float*)d_in[3];
  const float* bcp    = (const float*)d_in[4];
  const float* Wm     = (const float*)d_in[5];
  const float* bm     = (const float*)d_in[6];
  const float* Whpost = (const float*)d_in[7];
  const float* bhpost = (const float*)d_in[8];
  const float* Wr1    = (const float*)d_in[9];
  const float* br1    = (const float*)d_in[10];
  const float* Wr2    = (const float*)d_in[11];
  const float* br2    = (const float*)d_in[12];
  __bf16* wsp = (__bf16*)d_ws;
  float*  out = (float*)d_out;

  if (ws_size < (size_t)TOT * sizeof(__bf16)) return;

  pack_weights<<<(TOT + 255) / 256, 256, 0, stream>>>(Whp, Wm, Wcp, Whpost, Wr1, wsp);
  rnn_seq<<<64, 512, 0, stream>>>(x, wsp, bhp, bcp, bm, bhpost, br1, Wr2, br2, out);
}